// Round 1
// baseline (812.145 us; speedup 1.0000x reference)
//
#include <hip/hip_runtime.h>

// FamilyMLPLinear: per-class tiny MLP (16 -> 4 -> 1) over [B=512, C=17929].
// Memory-bound: x is 587 MB streamed once; weights ~5 MB cache-resident.
// v2: LDS-staged x tile via global_load_lds width=16 -> aligned 1KB bursts
// per wave-instruction instead of misaligned 256B dword bursts (C is odd,
// so direct per-lane loads can never be wider than 4B).

#define NUM_MODELS 16
#define HIDDEN 4
#define BATCH 512
#define NUM_CLASSES 17929
#define KB 16   // batches handled per block
#define CT 256  // classes per block (== blockDim.x)

typedef __attribute__((address_space(1))) const void as1_void;
typedef __attribute__((address_space(3))) void as3_void;

__global__ __launch_bounds__(CT) void FamilyMLPLinear_kernel(
    const float* __restrict__ x,    // [M, B, C]
    const float* __restrict__ W1,   // [C, H, M]
    const float* __restrict__ b1,   // [C, H]
    const float* __restrict__ W2,   // [C, H]
    const float* __restrict__ b2,   // [C]
    float* __restrict__ out)        // [B, C]
{
    __shared__ float xs[NUM_MODELS][CT];   // 16 KB staged x tile (one batch)

    const int t  = threadIdx.x;
    const int c0 = blockIdx.x * CT;
    const int b0 = blockIdx.y * KB;
    const int c  = c0 + t;
    // clamped class index for weight loads (only differs in the tail block)
    const int cw = (c < NUM_CLASSES) ? c : (NUM_CLASSES - 1);

    // ---- per-class weights into registers (vectorized, 16B-aligned) ----
    float w1[HIDDEN][NUM_MODELS];
    const float4* W1v = (const float4*)(W1 + (size_t)cw * (HIDDEN * NUM_MODELS));
    #pragma unroll
    for (int j = 0; j < HIDDEN; ++j) {
        #pragma unroll
        for (int q = 0; q < NUM_MODELS / 4; ++q) {
            float4 v = W1v[j * (NUM_MODELS / 4) + q];
            w1[j][q * 4 + 0] = v.x;
            w1[j][q * 4 + 1] = v.y;
            w1[j][q * 4 + 2] = v.z;
            w1[j][q * 4 + 3] = v.w;
        }
    }
    const float4 b1v = *(const float4*)(b1 + (size_t)cw * HIDDEN);
    const float bias1[HIDDEN] = {b1v.x, b1v.y, b1v.z, b1v.w};
    const float4 w2v = *(const float4*)(W2 + (size_t)cw * HIDDEN);
    const float w2[HIDDEN] = {w2v.x, w2v.y, w2v.z, w2v.w};
    const float bias2 = b2[cw];

    const size_t BC = (size_t)BATCH * NUM_CLASSES;

    if (c0 + CT <= NUM_CLASSES) {
        // ---------------- full c-tile: LDS-staged path ----------------
        const int lane = t & 63;
        const int wv   = t >> 6;    // wave id 0..3, stages rows 4wv..4wv+3

        #pragma unroll 1
        for (int bi = 0; bi < KB; ++bi) {
            const int b = b0 + bi;
            const size_t row0 = (size_t)b * NUM_CLASSES + c0; // dword idx (excl. m term)
            const int   sb  = (int)(row0 & 3);                // uniform per b (BC % 4 == 0)
            const size_t A0 = row0 - (size_t)sb;              // 16B-aligned dword start

            // stage 16 rows: one global_load_lds_dwordx4 per wave per row
            // (lane's 16B from aligned global addr -> xs[m][lane*4 .. lane*4+3])
            #pragma unroll
            for (int r = 0; r < 4; ++r) {
                const int m = wv * 4 + r;
                const float* gp = x + (size_t)m * BC + A0 + (size_t)(lane << 2);
                __builtin_amdgcn_global_load_lds((as1_void*)gp, (as3_void*)&xs[m][0],
                                                 16, 0, 0);
            }
            __syncthreads();   // drains vmcnt -> tile valid

            // gather this thread's class column (lane-contiguous: conflict-free)
            float xv[NUM_MODELS];
            const int ti = t + sb;
            if (ti < CT) {
                #pragma unroll
                for (int m = 0; m < NUM_MODELS; ++m) xv[m] = xs[m][ti];
            } else {
                // <=3 tail lanes slid past the staged window: direct loads
                const float* xp = x + row0 + t;
                #pragma unroll
                for (int m = 0; m < NUM_MODELS; ++m) xv[m] = xp[(size_t)m * BC];
            }

            // tiny MLP: 16 -> 4 (ReLU) -> 1
            float acc = bias2;
            #pragma unroll
            for (int j = 0; j < HIDDEN; ++j) {
                float h = bias1[j];
                #pragma unroll
                for (int m = 0; m < NUM_MODELS; ++m)
                    h = fmaf(xv[m], w1[j][m], h);
                h = fmaxf(h, 0.0f);
                acc = fmaf(h, w2[j], acc);
            }
            __builtin_nontemporal_store(acc, out + (size_t)b * NUM_CLASSES + c);
            __syncthreads();   // tile consumed; safe to restage next b
        }
    } else {
        // -------- tail c-block (9 classes at c0=17920): direct path --------
        if (c < NUM_CLASSES) {
            #pragma unroll 1
            for (int bi = 0; bi < KB; ++bi) {
                const int b = b0 + bi;
                const float* xp = x + (size_t)b * NUM_CLASSES + c;
                float xv[NUM_MODELS];
                #pragma unroll
                for (int m = 0; m < NUM_MODELS; ++m)
                    xv[m] = xp[(size_t)m * BC];
                float acc = bias2;
                #pragma unroll
                for (int j = 0; j < HIDDEN; ++j) {
                    float h = bias1[j];
                    #pragma unroll
                    for (int m = 0; m < NUM_MODELS; ++m)
                        h = fmaf(xv[m], w1[j][m], h);
                    h = fmaxf(h, 0.0f);
                    acc = fmaf(h, w2[j], acc);
                }
                out[(size_t)b * NUM_CLASSES + c] = acc;
            }
        }
    }
}

extern "C" void kernel_launch(void* const* d_in, const int* in_sizes, int n_in,
                              void* d_out, int out_size, void* d_ws, size_t ws_size,
                              hipStream_t stream) {
    const float* x  = (const float*)d_in[0];
    const float* W1 = (const float*)d_in[1];
    const float* b1 = (const float*)d_in[2];
    const float* W2 = (const float*)d_in[3];
    const float* b2 = (const float*)d_in[4];
    float* out = (float*)d_out;

    dim3 grid((NUM_CLASSES + CT - 1) / CT, BATCH / KB);
    FamilyMLPLinear_kernel<<<grid, CT, 0, stream>>>(x, W1, b1, W2, b2, out);
}

// Round 2
// 768.041 us; speedup vs baseline: 1.0574x; 1.0574x over previous
//
#include <hip/hip_runtime.h>

// FamilyMLPLinear: per-class tiny MLP (16 -> 4 -> 1) over [B=512, C=17929].
// Memory-bound: x is 587 MB streamed once; weights ~5 MB cache-resident.
// v3: double-buffered LDS staging via global_load_lds (aligned 1KB bursts)
// with RAW s_barrier + counted vmcnt(N) -- loads stay in flight across the
// barrier (v2's __syncthreads drained vmcnt to 0 every batch and regressed).

#define NUM_MODELS 16
#define HIDDEN 4
#define BATCH 512
#define NUM_CLASSES 17929
#define KB 16      // batches handled per block
#define CT 256     // classes per block (== blockDim.x)
#define ROWPAD 264 // LDS row stride in dwords (256 data + 4 spill + pad)

typedef __attribute__((address_space(1))) const void as1_void;
typedef __attribute__((address_space(3))) void as3_void;

#define ASM_VMCNT(n) asm volatile("s_waitcnt vmcnt(" #n ")" ::: "memory")
#define ASM_BARRIER() asm volatile("s_barrier" ::: "memory")

__global__ __launch_bounds__(CT) void FamilyMLPLinear_kernel(
    const float* __restrict__ x,    // [M, B, C]
    const float* __restrict__ W1,   // [C, H, M]
    const float* __restrict__ b1,   // [C, H]
    const float* __restrict__ W2,   // [C, H]
    const float* __restrict__ b2,   // [C]
    float* __restrict__ out)        // [B, C]
{
    __shared__ float xs[2][NUM_MODELS][ROWPAD];   // 33 KB double-buffered tile

    const int t    = threadIdx.x;
    const int lane = t & 63;
    const int wv   = t >> 6;            // wave id 0..3, stages rows 4wv..4wv+3
    const int c0   = blockIdx.x * CT;
    const int b0   = blockIdx.y * KB;
    const int c    = c0 + t;
    const int cw   = (c < NUM_CLASSES) ? c : (NUM_CLASSES - 1);

    // ---- per-class weights into registers (vectorized, 16B-aligned) ----
    float w1[HIDDEN][NUM_MODELS];
    const float4* W1v = (const float4*)(W1 + (size_t)cw * (HIDDEN * NUM_MODELS));
    #pragma unroll
    for (int j = 0; j < HIDDEN; ++j) {
        #pragma unroll
        for (int q = 0; q < NUM_MODELS / 4; ++q) {
            float4 v = W1v[j * (NUM_MODELS / 4) + q];
            w1[j][q * 4 + 0] = v.x;
            w1[j][q * 4 + 1] = v.y;
            w1[j][q * 4 + 2] = v.z;
            w1[j][q * 4 + 3] = v.w;
        }
    }
    const float4 b1v = *(const float4*)(b1 + (size_t)cw * HIDDEN);
    const float bias1[HIDDEN] = {b1v.x, b1v.y, b1v.z, b1v.w};
    const float4 w2v = *(const float4*)(W2 + (size_t)cw * HIDDEN);
    const float w2[HIDDEN] = {w2v.x, w2v.y, w2v.z, w2v.w};
    const float bias2 = b2[cw];

    const size_t BC = (size_t)BATCH * NUM_CLASSES;

    if (c0 + CT <= NUM_CLASSES) {
        // ---------------- full c-tile: pipelined LDS-staged path ----------------

        // stage batch b's 16 rows into buffer `buf`:
        //  per wave: 4x global_load_lds width=16 (aligned 1KB burst -> cols 0..255)
        //          + 4x global_load_lds width=4 on lanes 0..3 (cols 256..259)
        //  => exactly 8 vmem ops per wave per stage (vmcnt accounting relies on it)
        auto stage = [&](int buf, int b) {
            const size_t row0 = (size_t)b * NUM_CLASSES + c0;  // dword index
            const size_t A0   = row0 & ~(size_t)3;             // 16B-aligned start
            #pragma unroll
            for (int r = 0; r < 4; ++r) {
                const int m = wv * 4 + r;
                const float* gp = x + (size_t)m * BC + A0 + (size_t)(lane << 2);
                __builtin_amdgcn_global_load_lds((as1_void*)gp,
                                                 (as3_void*)&xs[buf][m][0], 16, 0, 0);
            }
            if (lane < 4) {   // 4 spill dwords per row (always in-bounds: <= row end)
                #pragma unroll
                for (int r = 0; r < 4; ++r) {
                    const int m = wv * 4 + r;
                    const float* gp2 = x + (size_t)m * BC + A0 + 256 + (size_t)lane;
                    __builtin_amdgcn_global_load_lds((as1_void*)gp2,
                                                     (as3_void*)&xs[buf][m][256], 4, 0, 0);
                }
            }
        };

        auto computeStore = [&](int buf, int b) {
            const int ti = t + (b & 3);   // sb = (b*C + c0) & 3 = b & 3
            float xv[NUM_MODELS];
            #pragma unroll
            for (int m = 0; m < NUM_MODELS; ++m)
                xv[m] = xs[buf][m][ti];
            float acc = bias2;
            #pragma unroll
            for (int j = 0; j < HIDDEN; ++j) {
                float h = bias1[j];
                #pragma unroll
                for (int m = 0; m < NUM_MODELS; ++m)
                    h = fmaf(xv[m], w1[j][m], h);
                h = fmaxf(h, 0.0f);
                acc = fmaf(h, w2[j], acc);
            }
            __builtin_nontemporal_store(acc, out + (size_t)b * NUM_CLASSES + c);
        };

        // prologue: fill buffer 0, full drain once
        stage(0, b0);
        ASM_VMCNT(0);
        ASM_BARRIER();
        __builtin_amdgcn_sched_barrier(0);

        // steady state: stage next tile, wait only for CURRENT tile's loads
        // (vmcnt(9) = newest 9 allowed in flight: 8 just-issued stage loads +
        //  previous iteration's output store; everything older has landed)
        #pragma unroll 1
        for (int bi = 0; bi < KB - 1; ++bi) {
            stage((bi + 1) & 1, b0 + bi + 1);
            ASM_VMCNT(9);
            ASM_BARRIER();
            __builtin_amdgcn_sched_barrier(0);
            computeStore(bi & 1, b0 + bi);
            __builtin_amdgcn_sched_barrier(0);
            ASM_BARRIER();   // all waves done reading this buffer before reuse
        }

        // epilogue: last tile (only the previous store may remain in flight)
        ASM_VMCNT(1);
        ASM_BARRIER();
        __builtin_amdgcn_sched_barrier(0);
        computeStore((KB - 1) & 1, b0 + KB - 1);
    } else {
        // -------- tail c-block (9 classes at c0=17920): direct path, no barriers --------
        if (c < NUM_CLASSES) {
            #pragma unroll 1
            for (int bi = 0; bi < KB; ++bi) {
                const int b = b0 + bi;
                const float* xp = x + (size_t)b * NUM_CLASSES + c;
                float xv[NUM_MODELS];
                #pragma unroll
                for (int m = 0; m < NUM_MODELS; ++m)
                    xv[m] = xp[(size_t)m * BC];
                float acc = bias2;
                #pragma unroll
                for (int j = 0; j < HIDDEN; ++j) {
                    float h = bias1[j];
                    #pragma unroll
                    for (int m = 0; m < NUM_MODELS; ++m)
                        h = fmaf(xv[m], w1[j][m], h);
                    h = fmaxf(h, 0.0f);
                    acc = fmaf(h, w2[j], acc);
                }
                out[(size_t)b * NUM_CLASSES + c] = acc;
            }
        }
    }
}

extern "C" void kernel_launch(void* const* d_in, const int* in_sizes, int n_in,
                              void* d_out, int out_size, void* d_ws, size_t ws_size,
                              hipStream_t stream) {
    const float* x  = (const float*)d_in[0];
    const float* W1 = (const float*)d_in[1];
    const float* b1 = (const float*)d_in[2];
    const float* W2 = (const float*)d_in[3];
    const float* b2 = (const float*)d_in[4];
    float* out = (float*)d_out;

    dim3 grid((NUM_CLASSES + CT - 1) / CT, BATCH / KB);
    FamilyMLPLinear_kernel<<<grid, CT, 0, stream>>>(x, W1, b1, W2, b2, out);
}